// Round 1
// 330.810 us; speedup vs baseline: 1.0662x; 1.0662x over previous
//
#include <hip/hip_runtime.h>

#define TSEQ 2048
#define BB 4
#define CDIM 1024
#define NH 16
#define HD 64
#define MR (TSEQ*BB)   // 8192 rows
#define C2SCALE 0.045084220f   // log2(e)/sqrt(CDIM) = log2(e)/32

typedef __attribute__((ext_vector_type(8))) short sh8;   // 8 bf16 = 4 VGPRs
typedef __attribute__((ext_vector_type(4))) short sh4;   // 4 bf16
typedef __attribute__((ext_vector_type(4))) float f4;    // MFMA C/D
typedef __attribute__((ext_vector_type(4))) unsigned int u32x4;

__device__ __forceinline__ unsigned short f2bf(float x){
  unsigned u = __builtin_bit_cast(unsigned, x);
  u += 0x7fffu + ((u>>16)&1u);          // round-to-nearest-even
  return (unsigned short)(u>>16);
}

// pack two floats -> two bf16 (round-half-up) in one dword: [hi16(a) : hi16(b)]
__device__ __forceinline__ unsigned pk2(float a, float b){
  unsigned ua = __builtin_bit_cast(unsigned, a) + 0x8000u;
  unsigned ub = __builtin_bit_cast(unsigned, b) + 0x8000u;
  return __builtin_amdgcn_perm(ua, ub, 0x07060302u);  // bytes a[3],a[2],b[3],b[2]
}

__device__ __forceinline__ void gll16(const unsigned short* g, unsigned short* l){
  __builtin_amdgcn_global_load_lds(
      (const __attribute__((address_space(1))) unsigned int*)g,
      (__attribute__((address_space(3))) unsigned int*)l, 16, 0, 0);
}

// ---------------- fp32 -> bf16 conversion, fused ----------------
__global__ void conv_x(const float* __restrict__ a, const float* __restrict__ b,
                       unsigned short* __restrict__ ya, unsigned short* __restrict__ yb){
  const float* s = blockIdx.y ? b : a;
  unsigned short* d = blockIdx.y ? yb : ya;
  int i = (blockIdx.x*256 + threadIdx.x)*4;
  f4 v = *(const f4*)(s+i);
  sh4 o;
  o.x = (short)f2bf(v.x); o.y = (short)f2bf(v.y);
  o.z = (short)f2bf(v.z); o.w = (short)f2bf(v.w);
  *(sh4*)(d+i) = o;
}

__global__ void conv_w(const float* __restrict__ w0, const float* __restrict__ w1,
                       const float* __restrict__ w2, const float* __restrict__ w3,
                       unsigned short* __restrict__ y0, unsigned short* __restrict__ y1,
                       unsigned short* __restrict__ y2, unsigned short* __restrict__ y3){
  const float* s; unsigned short* d;
  switch(blockIdx.y){
    case 0: s=w0; d=y0; break;
    case 1: s=w1; d=y1; break;
    case 2: s=w2; d=y2; break;
    default: s=w3; d=y3; break;
  }
  int i = (blockIdx.x*256 + threadIdx.x)*4;
  f4 v = *(const f4*)(s+i);
  sh4 o;
  o.x = (short)f2bf(v.x); o.y = (short)f2bf(v.y);
  o.z = (short)f2bf(v.z); o.w = (short)f2bf(v.w);
  *(sh4*)(d+i) = o;
}

// ---------------- final GEMM: C[m][n] = sum_k A[m][k]*W[n][k] + bias[n], fp32 out ----
__global__ __launch_bounds__(256,2) void gemm_u(
    const unsigned short* __restrict__ A, const unsigned short* __restrict__ Bw,
    const float* __restrict__ bias, float* __restrict__ Cout){
  __shared__ unsigned short As[128*32];
  __shared__ unsigned short Bs[128*32];
  const int tid  = threadIdx.x;
  const int wave = tid>>6, lane = tid&63;
  const int g = lane>>4, c = lane&15;
  const int m0 = blockIdx.x*128, n0 = blockIdx.y*128;
  const int wr = wave>>1, wc = wave&1;
  f4 acc[4][4] = {};
  const int r0 = tid>>2, cc0 = tid&3;
  const unsigned short* Ag = A  + (size_t)(m0+r0)*CDIM + cc0*8;
  const unsigned short* Bg = Bw + (size_t)(n0+r0)*CDIM + cc0*8;

  for (int k0=0; k0<CDIM; k0+=32){
    __syncthreads();
    gll16(Ag + k0,                    As + tid*8);
    gll16(Ag + (size_t)64*CDIM + k0,  As + (256+tid)*8);
    gll16(Bg + k0,                    Bs + tid*8);
    gll16(Bg + (size_t)64*CDIM + k0,  Bs + (256+tid)*8);
    __syncthreads();
    sh8 af[4], bfr[4];
#pragma unroll
    for (int mt=0; mt<4; mt++) af[mt]  = *(const sh8*)(As + (wr*64+mt*16+c)*32 + g*8);
#pragma unroll
    for (int nt=0; nt<4; nt++) bfr[nt] = *(const sh8*)(Bs + (wc*64+nt*16+c)*32 + g*8);
#pragma unroll
    for (int mt=0; mt<4; mt++)
#pragma unroll
      for (int nt=0; nt<4; nt++)
        acc[mt][nt] = __builtin_amdgcn_mfma_f32_16x16x32_bf16(af[mt], bfr[nt], acc[mt][nt], 0,0,0);
  }

#pragma unroll
  for (int nt=0; nt<4; nt++){
    int nn = n0 + wc*64 + nt*16 + c;
    float bsv = bias[nn];
#pragma unroll
    for (int mt=0; mt<4; mt++){
      int mb = m0 + wr*64 + mt*16 + 4*g;
#pragma unroll
      for (int r=0; r<4; r++)
        Cout[(size_t)(mb+r)*CDIM + nn] = acc[mt][nt][r] + bsv;
    }
  }
}

// ---------------- fused Q/K/V projection: blockIdx.z selects output ----------------
// z=0: Q = x1@Wq^T+bq, scaled by C2SCALE, bf16 row-major
// z=1: K = x2@Wk^T+bk, bf16 row-major
// z=2: V = x2@Wv^T+bv, bf16 transposed to (b,h,d,t)
// 1536 blocks (6/CU) vs two grid-starved launches at 2/CU.
__global__ __launch_bounds__(256,2) void gemm_qkv(
    const unsigned short* __restrict__ x1b, const unsigned short* __restrict__ x2b,
    const unsigned short* __restrict__ wq, const unsigned short* __restrict__ wk,
    const unsigned short* __restrict__ wv,
    const float* __restrict__ bq, const float* __restrict__ bk, const float* __restrict__ bv,
    unsigned short* __restrict__ Qo, unsigned short* __restrict__ Ko,
    unsigned short* __restrict__ Vo){
  __shared__ unsigned short As[128*32];
  __shared__ unsigned short Bs[128*32];
  const int z = blockIdx.z;
  const unsigned short* A  = (z==0) ? x1b : x2b;
  const unsigned short* Bw = (z==0) ? wq : (z==1) ? wk : wv;
  const float* bias        = (z==0) ? bq : (z==1) ? bk : bv;
  const int tid  = threadIdx.x;
  const int wave = tid>>6, lane = tid&63;
  const int g = lane>>4, c = lane&15;
  const int m0 = blockIdx.x*128, n0 = blockIdx.y*128;
  const int wr = wave>>1, wc = wave&1;
  f4 acc[4][4] = {};
  const int r0 = tid>>2, cc0 = tid&3;
  const unsigned short* Ag = A  + (size_t)(m0+r0)*CDIM + cc0*8;
  const unsigned short* Bg = Bw + (size_t)(n0+r0)*CDIM + cc0*8;

  for (int k0=0; k0<CDIM; k0+=32){
    __syncthreads();
    gll16(Ag + k0,                    As + tid*8);
    gll16(Ag + (size_t)64*CDIM + k0,  As + (256+tid)*8);
    gll16(Bg + k0,                    Bs + tid*8);
    gll16(Bg + (size_t)64*CDIM + k0,  Bs + (256+tid)*8);
    __syncthreads();
    sh8 af[4], bfr[4];
#pragma unroll
    for (int mt=0; mt<4; mt++) af[mt]  = *(const sh8*)(As + (wr*64+mt*16+c)*32 + g*8);
#pragma unroll
    for (int nt=0; nt<4; nt++) bfr[nt] = *(const sh8*)(Bs + (wc*64+nt*16+c)*32 + g*8);
#pragma unroll
    for (int mt=0; mt<4; mt++)
#pragma unroll
      for (int nt=0; nt<4; nt++)
        acc[mt][nt] = __builtin_amdgcn_mfma_f32_16x16x32_bf16(af[mt], bfr[nt], acc[mt][nt], 0,0,0);
  }

#pragma unroll
  for (int nt=0; nt<4; nt++){
    int nn = n0 + wc*64 + nt*16 + c;
    float bsv = bias[nn];
#pragma unroll
    for (int mt=0; mt<4; mt++){
      int mb = m0 + wr*64 + mt*16 + 4*g;
#pragma unroll
      for (int r=0; r<4; r++){
        float v = acc[mt][nt][r] + bsv;
        int mm = mb + r;
        if (z==0){
          Qo[(size_t)mm*CDIM + nn] = f2bf(v*C2SCALE);
        } else if (z==1){
          Ko[(size_t)mm*CDIM + nn] = f2bf(v);
        } else {
          int t = mm>>2, bb = mm&3, h = nn>>6, d = nn&63;
          Vo[(((size_t)bb*NH + h)*HD + d)*TSEQ + t] = f2bf(v);
        }
      }
    }
  }
}

// ---------------- flash attention, S^T / O^T, register-pipelined staging --------
// Round-8 change: the Ps LDS round-trip (P pack -> ds_write -> ds_read as PV
// B-fragment) is replaced by an in-register transpose:
//   - 2x v_permlane32_swap_b32 exchanges the kf-pair across lane halves
//   - 4x ds_swizzle xor-16 moves data between g and g^1 groups
//   - cndmask by g-parity assembles the final B-fragment dwords
// This removes 16 ds_write_b64 + 8 ds_read_b128 per wave-iter and 16KB LDS
// (48KB -> 32KB). S is now computed/consumed per 64-key half (sacc[4][2]
// instead of [8][2], -32 accumulator regs) so total regs fit 3 blocks/CU
// (round-7 was register-limited to 2 blocks = Occupancy 25.7%). setprio(1)
// wraps the MFMA clusters (T5, attn-positive per m191).
__global__ __launch_bounds__(256,3) void attn_kernel(
    const unsigned short* __restrict__ Q, const unsigned short* __restrict__ Kb,
    const unsigned short* __restrict__ Vt, unsigned short* __restrict__ O){
  __shared__ unsigned short Ks[128*64];        // (key, d), chunk ^= row&7
  __shared__ unsigned short Vs[64*128];        // (d, key), chunk ^= d&15
  const int tid=threadIdx.x, wave=tid>>6, lane=tid&63;
  const int g=lane>>4, c=lane&15;
  const bool godd = (g&1);
  const int gx = blockIdx.x;                   // 1024 linear blocks
  const int bh = ((gx>>7)<<3) | (gx&7);        // all 16 qts of a bh share gx%8 (same XCD)
  const int qt = (gx>>3)&15;
  const int b = bh>>4, h = bh&15;
  const int qbase = qt*128 + wave*32;

  // staging address bases (k0-invariant parts)
  const unsigned short* kbase[4];
  const unsigned short* vbase[4];
#pragma unroll
  for (int i=0; i<4; i++){
    int cc = i*256+tid;
    int krow = cc>>3, kch = (cc&7) ^ (krow&7);
    kbase[i] = Kb + ((size_t)krow*BB + b)*CDIM + h*HD + kch*8;
    int vd = cc>>4, vch = (cc&15) ^ (vd&15);
    vbase[i] = Vt + ((size_t)(b*NH+h)*HD + vd)*TSEQ + vch*8;
  }

  sh8 qfr[2][2];
#pragma unroll
  for (int qf=0; qf<2; qf++)
#pragma unroll
    for (int kc=0; kc<2; kc++){
      int t = qbase + qf*16 + c;
      qfr[qf][kc] = *(const sh8*)(Q + ((size_t)t*BB + b)*CDIM + h*HD + kc*32 + g*8);
    }

  f4 oacc[4][2] = {};                          // O^T frags: [d-frag][q-frag]
  float lrun[2] = {0.f, 0.f};                  // lane-local partial denominators

  // prologue: load tile 0 -> regs -> LDS
  f4 kreg[4], vreg[4];
#pragma unroll
  for (int i=0; i<4; i++){
    kreg[i] = *(const f4*)(kbase[i]);
    vreg[i] = *(const f4*)(vbase[i]);
  }
#pragma unroll
  for (int i=0; i<4; i++){
    *(f4*)(Ks + (i*256+tid)*8) = kreg[i];
    *(f4*)(Vs + (i*256+tid)*8) = vreg[i];
  }
  __syncthreads();

  for (int iter=0; iter<TSEQ/128; iter++){
    // issue next tile's global loads (in flight during compute below)
    if (iter < TSEQ/128-1){
      int k0n = (iter+1)*128;
#pragma unroll
      for (int i=0; i<4; i++){
        kreg[i] = *(const f4*)(kbase[i] + (size_t)k0n*BB*CDIM);
        vreg[i] = *(const f4*)(vbase[i] + k0n);
      }
    }

    // ---- compute on current LDS tile, one 64-key half at a time ----
    // S^T = K * Q^T : lane holds key=16kf+4g+r, q=16qf+c
#pragma unroll
    for (int half=0; half<2; half++){
      f4 sacc[4][2] = {};
      __builtin_amdgcn_s_setprio(1);
#pragma unroll
      for (int kfl=0; kfl<4; kfl++){
        int kf = half*4 + kfl;
        sh8 af[2];
#pragma unroll
        for (int kc=0; kc<2; kc++){
          int ch = (kc*4+g) ^ (c&7);
          af[kc] = *(const sh8*)(Ks + (kf*16+c)*64 + ch*8);
        }
#pragma unroll
        for (int kc=0; kc<2; kc++)
#pragma unroll
          for (int qf=0; qf<2; qf++)
            sacc[kfl][qf] = __builtin_amdgcn_mfma_f32_16x16x32_bf16(af[kc], qfr[qf][kc], sacc[kfl][qf],0,0,0);
      }
      __builtin_amdgcn_s_setprio(0);

      // exp2 + in-register transpose -> PV B-fragments, then PV MFMA
#pragma unroll
      for (int kc2l=0; kc2l<2; kc2l++){
        const int kc2 = half*2 + kc2l;
        sh8 pf[2];
#pragma unroll
        for (int qf=0; qf<2; qf++){
          f4 sa = sacc[2*kc2l][qf];
          f4 sb = sacc[2*kc2l+1][qf];
          float pa0 = __builtin_amdgcn_exp2f(sa[0]);
          float pa1 = __builtin_amdgcn_exp2f(sa[1]);
          float pa2 = __builtin_amdgcn_exp2f(sa[2]);
          float pa3 = __builtin_amdgcn_exp2f(sa[3]);
          float pb0 = __builtin_amdgcn_exp2f(sb[0]);
          float pb1 = __builtin_amdgcn_exp2f(sb[1]);
          float pb2 = __builtin_amdgcn_exp2f(sb[2]);
          float pb3 = __builtin_amdgcn_exp2f(sb[3]);
          lrun[qf] += ((pa0+pa1)+(pa2+pa3)) + ((pb0+pb1)+(pb2+pb3));
          // dwords: low short = even key, high short = odd key
          unsigned A0 = pk2(pa1, pa0);   // keys 4g+{0,1} of kf=2*kc2
          unsigned A1 = pk2(pa3, pa2);   // keys 4g+{2,3}
          unsigned B0 = pk2(pb1, pb0);   // keys 4g+{0,1} of kf=2*kc2+1
          unsigned B1 = pk2(pb3, pb2);
          // exchange: A' = {A.lo32lanes ; B.lo32lanes}, B' = {A.hi ; B.hi}
          asm("v_permlane32_swap_b32 %0, %1" : "+v"(A0), "+v"(B0));
          asm("v_permlane32_swap_b32 %0, %1" : "+v"(A1), "+v"(B1));
          // g <-> g^1 movement (xor 16 within each 32-lane half)
          unsigned xA0 = (unsigned)__builtin_amdgcn_ds_swizzle((int)A0, 0x401F);
          unsigned xA1 = (unsigned)__builtin_amdgcn_ds_swizzle((int)A1, 0x401F);
          unsigned xB0 = (unsigned)__builtin_amdgcn_ds_swizzle((int)B0, 0x401F);
          unsigned xB1 = (unsigned)__builtin_amdgcn_ds_swizzle((int)B1, 0x401F);
          u32x4 pw;
          pw.x = godd ? xB0 : A0;   // keys g*8+{0,1}
          pw.y = godd ? xB1 : A1;   // keys g*8+{2,3}
          pw.z = godd ? B0  : xA0;  // keys g*8+{4,5}
          pw.w = godd ? B1  : xA1;  // keys g*8+{6,7}
          pf[qf] = __builtin_bit_cast(sh8, pw);
        }
        __builtin_amdgcn_s_setprio(1);
#pragma unroll
        for (int df=0; df<4; df++){
          int ch = (kc2*4+g) ^ c;
          sh8 vf = *(const sh8*)(Vs + (df*16+c)*128 + ch*8);
#pragma unroll
          for (int qf=0; qf<2; qf++)
            oacc[df][qf] = __builtin_amdgcn_mfma_f32_16x16x32_bf16(vf, pf[qf], oacc[df][qf],0,0,0);
        }
        __builtin_amdgcn_s_setprio(0);
      }
    }

    // ---- rotate: all waves done reading, then overwrite LDS with next tile ----
    __syncthreads();
    if (iter < TSEQ/128-1){
#pragma unroll
      for (int i=0; i<4; i++){
        *(f4*)(Ks + (i*256+tid)*8) = kreg[i];
        *(f4*)(Vs + (i*256+tid)*8) = vreg[i];
      }
      __syncthreads();
    }
  }

  // cross-lane denominator reduction (over g groups), then normalize + store
#pragma unroll
  for (int qf=0; qf<2; qf++){
    lrun[qf] += __shfl_xor(lrun[qf], 16, 64);
    lrun[qf] += __shfl_xor(lrun[qf], 32, 64);
    float inv = 1.0f/lrun[qf];
    int t = qbase + qf*16 + c;
#pragma unroll
    for (int df=0; df<4; df++){
      uint2 pr;
      pr.x = pk2(oacc[df][qf][1]*inv, oacc[df][qf][0]*inv);
      pr.y = pk2(oacc[df][qf][3]*inv, oacc[df][qf][2]*inv);
      *(uint2*)(O + ((size_t)b*TSEQ + t)*CDIM + h*HD + df*16 + 4*g) = pr;
    }
  }
}

extern "C" void kernel_launch(void* const* d_in, const int* in_sizes, int n_in,
                              void* d_out, int out_size, void* d_ws, size_t ws_size,
                              hipStream_t stream){
  (void)in_sizes; (void)n_in; (void)out_size; (void)ws_size;
  const float* x1 = (const float*)d_in[0];
  const float* x2 = (const float*)d_in[1];
  const float* Wq = (const float*)d_in[2];
  const float* bq = (const float*)d_in[3];
  const float* Wk = (const float*)d_in[4];
  const float* bk = (const float*)d_in[5];
  const float* Wv = (const float*)d_in[6];
  const float* bv = (const float*)d_in[7];
  const float* Wu = (const float*)d_in[8];
  const float* bu = (const float*)d_in[9];

  unsigned short* ws = (unsigned short*)d_ws;
  size_t o = 0;
  unsigned short* x1b = ws + o; o += (size_t)MR*CDIM;
  unsigned short* x2b = ws + o; o += (size_t)MR*CDIM;
  unsigned short* wqb = ws + o; o += (size_t)CDIM*CDIM;
  unsigned short* wkb = ws + o; o += (size_t)CDIM*CDIM;
  unsigned short* wvb = ws + o; o += (size_t)CDIM*CDIM;
  unsigned short* wub = ws + o; o += (size_t)CDIM*CDIM;
  unsigned short* Qb  = ws + o; o += (size_t)MR*CDIM;
  unsigned short* Kbf = ws + o; o += (size_t)MR*CDIM;
  unsigned short* Vtb = ws + o; o += (size_t)MR*CDIM;
  unsigned short* Ob  = x1b;   // x1b dead after QKV GEMM; reuse for attention output

  conv_x<<<dim3((MR*CDIM)/1024, 2),   256, 0, stream>>>(x1, x2, x1b, x2b);
  conv_w<<<dim3((CDIM*CDIM)/1024, 4), 256, 0, stream>>>(Wq, Wk, Wv, Wu, wqb, wkb, wvb, wub);

  gemm_qkv<<<dim3(MR/128, CDIM/128, 3), 256, 0, stream>>>(
      x1b, x2b, wqb, wkb, wvb, bq, bk, bv, Qb, Kbf, Vtb);
  attn_kernel<<<dim3(1024), 256, 0, stream>>>(Qb, Kbf, Vtb, Ob);
  gemm_u<<<dim3(MR/128, CDIM/128), 256, 0, stream>>>(Ob, wub, bu, (float*)d_out);
}

// Round 2
// 330.606 us; speedup vs baseline: 1.0669x; 1.0006x over previous
//
#include <hip/hip_runtime.h>

#define TSEQ 2048
#define BB 4
#define CDIM 1024
#define NH 16
#define HD 64
#define MR (TSEQ*BB)   // 8192 rows
#define C2SCALE 0.045084220f   // log2(e)/sqrt(CDIM) = log2(e)/32

typedef __attribute__((ext_vector_type(8))) short sh8;   // 8 bf16 = 4 VGPRs
typedef __attribute__((ext_vector_type(4))) short sh4;   // 4 bf16
typedef __attribute__((ext_vector_type(4))) float f4;    // MFMA C/D
typedef __attribute__((ext_vector_type(4))) unsigned int u32x4;

__device__ __forceinline__ unsigned short f2bf(float x){
  unsigned u = __builtin_bit_cast(unsigned, x);
  u += 0x7fffu + ((u>>16)&1u);          // round-to-nearest-even
  return (unsigned short)(u>>16);
}

// pack two floats -> two bf16 (round-half-up) in one dword: [hi16(a) : hi16(b)]
__device__ __forceinline__ unsigned pk2(float a, float b){
  unsigned ua = __builtin_bit_cast(unsigned, a) + 0x8000u;
  unsigned ub = __builtin_bit_cast(unsigned, b) + 0x8000u;
  return __builtin_amdgcn_perm(ua, ub, 0x07060302u);  // bytes a[3],a[2],b[3],b[2]
}

__device__ __forceinline__ void gll16(const unsigned short* g, unsigned short* l){
  __builtin_amdgcn_global_load_lds(
      (const __attribute__((address_space(1))) unsigned int*)g,
      (__attribute__((address_space(3))) unsigned int*)l, 16, 0, 0);
}

// ---------------- fp32 -> bf16 conversion, fused ----------------
__global__ void conv_x(const float* __restrict__ a, const float* __restrict__ b,
                       unsigned short* __restrict__ ya, unsigned short* __restrict__ yb){
  const float* s = blockIdx.y ? b : a;
  unsigned short* d = blockIdx.y ? yb : ya;
  int i = (blockIdx.x*256 + threadIdx.x)*4;
  f4 v = *(const f4*)(s+i);
  sh4 o;
  o.x = (short)f2bf(v.x); o.y = (short)f2bf(v.y);
  o.z = (short)f2bf(v.z); o.w = (short)f2bf(v.w);
  *(sh4*)(d+i) = o;
}

__global__ void conv_w(const float* __restrict__ w0, const float* __restrict__ w1,
                       const float* __restrict__ w2, const float* __restrict__ w3,
                       unsigned short* __restrict__ y0, unsigned short* __restrict__ y1,
                       unsigned short* __restrict__ y2, unsigned short* __restrict__ y3){
  const float* s; unsigned short* d;
  switch(blockIdx.y){
    case 0: s=w0; d=y0; break;
    case 1: s=w1; d=y1; break;
    case 2: s=w2; d=y2; break;
    default: s=w3; d=y3; break;
  }
  int i = (blockIdx.x*256 + threadIdx.x)*4;
  f4 v = *(const f4*)(s+i);
  sh4 o;
  o.x = (short)f2bf(v.x); o.y = (short)f2bf(v.y);
  o.z = (short)f2bf(v.z); o.w = (short)f2bf(v.w);
  *(sh4*)(d+i) = o;
}

// ================= deep-pipelined GEMM core =================
// BM=256, BN=128, BK=64, 512 threads = 8 waves (4M x 2N), per-wave 64x64.
// 3-deep LDS ring buffer (3 x 48KB = 144KB), stages 2 K-tiles ahead with
// counted s_waitcnt vmcnt(6) (never 0 in steady state) + raw s_barriers.
// LDS chunk-swizzle ch ^= row&7 applied on the GLOBAL source address
// (global_load_lds dest stays linear) and on the ds_read address.
// Race windows: buf q (tile kt) is overwritten by tile kt+3's stage issued at
// ph1 of kt+1, i.e. after kt's final barrier (all reads lgkm-drained before
// their MFMA, which precedes that barrier). vmcnt(6) at each tile's end
// guarantees tile kt+1 has landed before its ph1 reads.
#define NKT 16          // CDIM/64
#define BUFS 24576      // shorts per ring slot (A 16384 + B 8192)

__device__ __forceinline__ void gemm_core(
    const unsigned short* __restrict__ Aglob, const unsigned short* __restrict__ Bglob,
    unsigned short* smem, int m0, int n0, int tid, f4 (&acc)[4][4])
{
  const int wave = tid>>6, lane = tid&63;
  const int g = lane>>4, c = lane&15;
  const int wr = wave>>1, wc = wave&1;

  // staging precompute: A slots i*512+tid (i<4), B slots i*512+tid (i<2)
  const unsigned short* aSrc[4]; int aOff[4];
  const unsigned short* bSrc[2]; int bOff[2];
#pragma unroll
  for (int i=0;i<4;i++){
    int slot = i*512+tid; int row = slot>>3, ch = slot&7;
    aSrc[i] = Aglob + (size_t)(m0+row)*CDIM + (ch^(row&7))*8;
    aOff[i] = slot*8;
  }
#pragma unroll
  for (int i=0;i<2;i++){
    int slot = i*512+tid; int row = slot>>3, ch = slot&7;
    bSrc[i] = Bglob + (size_t)(n0+row)*CDIM + (ch^(row&7))*8;
    bOff[i] = 16384 + slot*8;
  }
  const int arow = wr*64 + c;        // + mt*16
  const int brow = wc*64 + c;        // + nt*16
  const int ch0 = g ^ (c&7);         // ks=0 swizzled chunk
  const int ch1 = (4+g) ^ (c&7);     // ks=1

  // prologue: stage tiles 0 and 1
#pragma unroll
  for (int i=0;i<4;i++) gll16(aSrc[i],     smem + aOff[i]);
#pragma unroll
  for (int i=0;i<2;i++) gll16(bSrc[i],     smem + bOff[i]);
#pragma unroll
  for (int i=0;i<4;i++) gll16(aSrc[i]+64,  smem + BUFS + aOff[i]);
#pragma unroll
  for (int i=0;i<2;i++) gll16(bSrc[i]+64,  smem + BUFS + bOff[i]);
  asm volatile("s_waitcnt vmcnt(6)" ::: "memory");   // tile 0 landed
  __builtin_amdgcn_s_barrier();
  __builtin_amdgcn_sched_barrier(0);

  int q = 0;
  for (int kt=0; kt<NKT; kt++){
    unsigned short* bufc = smem + q*BUFS;
    int r = q+2; if (r>=3) r-=3;                 // stage target ring slot
    unsigned short* dst = smem + r*BUFS;
    const int koff = (kt+2)*64;
    // ---------- ph1: A frags + B n0-1, stage A of tile kt+2 ----------
    sh8 af[4][2], bfr[2][2];
#pragma unroll
    for (int mt=0;mt<4;mt++){
      af[mt][0] = *(const sh8*)(bufc + (arow+mt*16)*64 + ch0*8);
      af[mt][1] = *(const sh8*)(bufc + (arow+mt*16)*64 + ch1*8);
    }
#pragma unroll
    for (int nt=0;nt<2;nt++){
      bfr[nt][0] = *(const sh8*)(bufc + 16384 + (brow+nt*16)*64 + ch0*8);
      bfr[nt][1] = *(const sh8*)(bufc + 16384 + (brow+nt*16)*64 + ch1*8);
    }
    if (kt+2 < NKT){
#pragma unroll
      for (int i=0;i<4;i++) gll16(aSrc[i]+koff, dst + aOff[i]);
    }
    __builtin_amdgcn_s_barrier();
    __builtin_amdgcn_sched_barrier(0);
    __builtin_amdgcn_s_setprio(1);
#pragma unroll
    for (int mt=0;mt<4;mt++)
#pragma unroll
      for (int nt=0;nt<2;nt++){
        acc[mt][nt] = __builtin_amdgcn_mfma_f32_16x16x32_bf16(af[mt][0], bfr[nt][0], acc[mt][nt],0,0,0);
        acc[mt][nt] = __builtin_amdgcn_mfma_f32_16x16x32_bf16(af[mt][1], bfr[nt][1], acc[mt][nt],0,0,0);
      }
    __builtin_amdgcn_s_setprio(0);
    __builtin_amdgcn_s_barrier();
    __builtin_amdgcn_sched_barrier(0);
    // ---------- ph2: B n2-3, stage B of tile kt+2, counted vmcnt ----------
#pragma unroll
    for (int nt=0;nt<2;nt++){
      bfr[nt][0] = *(const sh8*)(bufc + 16384 + (brow+(nt+2)*16)*64 + ch0*8);
      bfr[nt][1] = *(const sh8*)(bufc + 16384 + (brow+(nt+2)*16)*64 + ch1*8);
    }
    if (kt+2 < NKT){
#pragma unroll
      for (int i=0;i<2;i++) gll16(bSrc[i]+koff, dst + bOff[i]);
    }
    __builtin_amdgcn_s_barrier();
    __builtin_amdgcn_sched_barrier(0);
    __builtin_amdgcn_s_setprio(1);
#pragma unroll
    for (int mt=0;mt<4;mt++)
#pragma unroll
      for (int nt=0;nt<2;nt++){
        acc[mt][nt+2] = __builtin_amdgcn_mfma_f32_16x16x32_bf16(af[mt][0], bfr[nt][0], acc[mt][nt+2],0,0,0);
        acc[mt][nt+2] = __builtin_amdgcn_mfma_f32_16x16x32_bf16(af[mt][1], bfr[nt][1], acc[mt][nt+2],0,0,0);
      }
    __builtin_amdgcn_s_setprio(0);
    if (kt < NKT-1){
      if (kt < NKT-2) asm volatile("s_waitcnt vmcnt(6)" ::: "memory");  // tile kt+1 landed
      else            asm volatile("s_waitcnt vmcnt(0)" ::: "memory");  // tail drain
    }
    __builtin_amdgcn_s_barrier();
    __builtin_amdgcn_sched_barrier(0);
    q = (q==2)?0:q+1;
  }
}

// ---------------- final GEMM: C[m][n] = sum_k A[m][k]*W[n][k] + bias[n], fp32 out ----
__global__ __launch_bounds__(512,2) void gemm_u(
    const unsigned short* __restrict__ A, const unsigned short* __restrict__ Bw,
    const float* __restrict__ bias, float* __restrict__ Cout){
  __shared__ unsigned short smem[3*BUFS];
  const int tid  = threadIdx.x;
  const int wave = tid>>6, lane = tid&63;
  const int g = lane>>4, c = lane&15;
  const int m0 = blockIdx.x*256, n0 = blockIdx.y*128;
  const int wr = wave>>1, wc = wave&1;
  f4 acc[4][4] = {};
  gemm_core(A, Bw, smem, m0, n0, tid, acc);

#pragma unroll
  for (int nt=0; nt<4; nt++){
    int nn = n0 + wc*64 + nt*16 + c;
    float bsv = bias[nn];
#pragma unroll
    for (int mt=0; mt<4; mt++){
      int mb = m0 + wr*64 + mt*16 + 4*g;
#pragma unroll
      for (int r=0; r<4; r++)
        Cout[(size_t)(mb+r)*CDIM + nn] = acc[mt][nt][r] + bsv;
    }
  }
}

// ---------------- fused Q/K/V projection: blockIdx.z selects output ----------------
// z=0: Q = x1@Wq^T+bq, scaled by C2SCALE, bf16 row-major
// z=1: K = x2@Wk^T+bk, bf16 row-major
// z=2: V = x2@Wv^T+bv, bf16 transposed to (b,h,d,t)
__global__ __launch_bounds__(512,2) void gemm_qkv(
    const unsigned short* __restrict__ x1b, const unsigned short* __restrict__ x2b,
    const unsigned short* __restrict__ wq, const unsigned short* __restrict__ wk,
    const unsigned short* __restrict__ wv,
    const float* __restrict__ bq, const float* __restrict__ bk, const float* __restrict__ bv,
    unsigned short* __restrict__ Qo, unsigned short* __restrict__ Ko,
    unsigned short* __restrict__ Vo){
  __shared__ unsigned short smem[3*BUFS];
  const int z = blockIdx.z;
  const unsigned short* A  = (z==0) ? x1b : x2b;
  const unsigned short* Bw = (z==0) ? wq : (z==1) ? wk : wv;
  const float* bias        = (z==0) ? bq : (z==1) ? bk : bv;
  const int tid  = threadIdx.x;
  const int wave = tid>>6, lane = tid&63;
  const int g = lane>>4, c = lane&15;
  const int m0 = blockIdx.x*256, n0 = blockIdx.y*128;
  const int wr = wave>>1, wc = wave&1;
  f4 acc[4][4] = {};
  gemm_core(A, Bw, smem, m0, n0, tid, acc);

#pragma unroll
  for (int nt=0; nt<4; nt++){
    int nn = n0 + wc*64 + nt*16 + c;
    float bsv = bias[nn];
#pragma unroll
    for (int mt=0; mt<4; mt++){
      int mb = m0 + wr*64 + mt*16 + 4*g;
#pragma unroll
      for (int r=0; r<4; r++){
        float v = acc[mt][nt][r] + bsv;
        int mm = mb + r;
        if (z==0){
          Qo[(size_t)mm*CDIM + nn] = f2bf(v*C2SCALE);
        } else if (z==1){
          Ko[(size_t)mm*CDIM + nn] = f2bf(v);
        } else {
          int t = mm>>2, bb = mm&3, h = nn>>6, d = nn&63;
          Vo[(((size_t)bb*NH + h)*HD + d)*TSEQ + t] = f2bf(v);
        }
      }
    }
  }
}

// ---------------- flash attention, S^T / O^T, register-pipelined staging --------
// In-register P transpose (permlane32_swap + ds_swizzle xor-16 + cndmask),
// per-half S accumulation, setprio around MFMA clusters. 32KB LDS, 3 blocks/CU.
__global__ __launch_bounds__(256,3) void attn_kernel(
    const unsigned short* __restrict__ Q, const unsigned short* __restrict__ Kb,
    const unsigned short* __restrict__ Vt, unsigned short* __restrict__ O){
  __shared__ unsigned short Ks[128*64];        // (key, d), chunk ^= row&7
  __shared__ unsigned short Vs[64*128];        // (d, key), chunk ^= d&15
  const int tid=threadIdx.x, wave=tid>>6, lane=tid&63;
  const int g=lane>>4, c=lane&15;
  const bool godd = (g&1);
  const int gx = blockIdx.x;                   // 1024 linear blocks
  const int bh = ((gx>>7)<<3) | (gx&7);        // all 16 qts of a bh share gx%8 (same XCD)
  const int qt = (gx>>3)&15;
  const int b = bh>>4, h = bh&15;
  const int qbase = qt*128 + wave*32;

  // staging address bases (k0-invariant parts)
  const unsigned short* kbase[4];
  const unsigned short* vbase[4];
#pragma unroll
  for (int i=0; i<4; i++){
    int cc = i*256+tid;
    int krow = cc>>3, kch = (cc&7) ^ (krow&7);
    kbase[i] = Kb + ((size_t)krow*BB + b)*CDIM + h*HD + kch*8;
    int vd = cc>>4, vch = (cc&15) ^ (vd&15);
    vbase[i] = Vt + ((size_t)(b*NH+h)*HD + vd)*TSEQ + vch*8;
  }

  sh8 qfr[2][2];
#pragma unroll
  for (int qf=0; qf<2; qf++)
#pragma unroll
    for (int kc=0; kc<2; kc++){
      int t = qbase + qf*16 + c;
      qfr[qf][kc] = *(const sh8*)(Q + ((size_t)t*BB + b)*CDIM + h*HD + kc*32 + g*8);
    }

  f4 oacc[4][2] = {};                          // O^T frags: [d-frag][q-frag]
  float lrun[2] = {0.f, 0.f};                  // lane-local partial denominators

  // prologue: load tile 0 -> regs -> LDS
  f4 kreg[4], vreg[4];
#pragma unroll
  for (int i=0; i<4; i++){
    kreg[i] = *(const f4*)(kbase[i]);
    vreg[i] = *(const f4*)(vbase[i]);
  }
#pragma unroll
  for (int i=0; i<4; i++){
    *(f4*)(Ks + (i*256+tid)*8) = kreg[i];
    *(f4*)(Vs + (i*256+tid)*8) = vreg[i];
  }
  __syncthreads();

  for (int iter=0; iter<TSEQ/128; iter++){
    // issue next tile's global loads (in flight during compute below)
    if (iter < TSEQ/128-1){
      int k0n = (iter+1)*128;
#pragma unroll
      for (int i=0; i<4; i++){
        kreg[i] = *(const f4*)(kbase[i] + (size_t)k0n*BB*CDIM);
        vreg[i] = *(const f4*)(vbase[i] + k0n);
      }
    }

    // ---- compute on current LDS tile, one 64-key half at a time ----
    // S^T = K * Q^T : lane holds key=16kf+4g+r, q=16qf+c
#pragma unroll
    for (int half=0; half<2; half++){
      f4 sacc[4][2] = {};
      __builtin_amdgcn_s_setprio(1);
#pragma unroll
      for (int kfl=0; kfl<4; kfl++){
        int kf = half*4 + kfl;
        sh8 af[2];
#pragma unroll
        for (int kc=0; kc<2; kc++){
          int ch = (kc*4+g) ^ (c&7);
          af[kc] = *(const sh8*)(Ks + (kf*16+c)*64 + ch*8);
        }
#pragma unroll
        for (int kc=0; kc<2; kc++)
#pragma unroll
          for (int qf=0; qf<2; qf++)
            sacc[kfl][qf] = __builtin_amdgcn_mfma_f32_16x16x32_bf16(af[kc], qfr[qf][kc], sacc[kfl][qf],0,0,0);
      }
      __builtin_amdgcn_s_setprio(0);

      // exp2 + in-register transpose -> PV B-fragments, then PV MFMA
#pragma unroll
      for (int kc2l=0; kc2l<2; kc2l++){
        const int kc2 = half*2 + kc2l;
        sh8 pf[2];
#pragma unroll
        for (int qf=0; qf<2; qf++){
          f4 sa = sacc[2*kc2l][qf];
          f4 sb = sacc[2*kc2l+1][qf];
          float pa0 = __builtin_amdgcn_exp2f(sa[0]);
          float pa1 = __builtin_amdgcn_exp2f(sa[1]);
          float pa2 = __builtin_amdgcn_exp2f(sa[2]);
          float pa3 = __builtin_amdgcn_exp2f(sa[3]);
          float pb0 = __builtin_amdgcn_exp2f(sb[0]);
          float pb1 = __builtin_amdgcn_exp2f(sb[1]);
          float pb2 = __builtin_amdgcn_exp2f(sb[2]);
          float pb3 = __builtin_amdgcn_exp2f(sb[3]);
          lrun[qf] += ((pa0+pa1)+(pa2+pa3)) + ((pb0+pb1)+(pb2+pb3));
          // dwords: low short = even key, high short = odd key
          unsigned A0 = pk2(pa1, pa0);   // keys 4g+{0,1} of kf=2*kc2
          unsigned A1 = pk2(pa3, pa2);   // keys 4g+{2,3}
          unsigned B0 = pk2(pb1, pb0);   // keys 4g+{0,1} of kf=2*kc2+1
          unsigned B1 = pk2(pb3, pb2);
          // exchange: A' = {A.lo32lanes ; B.lo32lanes}, B' = {A.hi ; B.hi}
          asm("v_permlane32_swap_b32 %0, %1" : "+v"(A0), "+v"(B0));
          asm("v_permlane32_swap_b32 %0, %1" : "+v"(A1), "+v"(B1));
          // g <-> g^1 movement (xor 16 within each 32-lane half)
          unsigned xA0 = (unsigned)__builtin_amdgcn_ds_swizzle((int)A0, 0x401F);
          unsigned xA1 = (unsigned)__builtin_amdgcn_ds_swizzle((int)A1, 0x401F);
          unsigned xB0 = (unsigned)__builtin_amdgcn_ds_swizzle((int)B0, 0x401F);
          unsigned xB1 = (unsigned)__builtin_amdgcn_ds_swizzle((int)B1, 0x401F);
          u32x4 pw;
          pw.x = godd ? xB0 : A0;   // keys g*8+{0,1}
          pw.y = godd ? xB1 : A1;   // keys g*8+{2,3}
          pw.z = godd ? B0  : xA0;  // keys g*8+{4,5}
          pw.w = godd ? B1  : xA1;  // keys g*8+{6,7}
          pf[qf] = __builtin_bit_cast(sh8, pw);
        }
        __builtin_amdgcn_s_setprio(1);
#pragma unroll
        for (int df=0; df<4; df++){
          int ch = (kc2*4+g) ^ c;
          sh8 vf = *(const sh8*)(Vs + (df*16+c)*128 + ch*8);
#pragma unroll
          for (int qf=0; qf<2; qf++)
            oacc[df][qf] = __builtin_amdgcn_mfma_f32_16x16x32_bf16(vf, pf[qf], oacc[df][qf],0,0,0);
        }
        __builtin_amdgcn_s_setprio(0);
      }
    }

    // ---- rotate: all waves done reading, then overwrite LDS with next tile ----
    __syncthreads();
    if (iter < TSEQ/128-1){
#pragma unroll
      for (int i=0; i<4; i++){
        *(f4*)(Ks + (i*256+tid)*8) = kreg[i];
        *(f4*)(Vs + (i*256+tid)*8) = vreg[i];
      }
      __syncthreads();
    }
  }

  // cross-lane denominator reduction (over g groups), then normalize + store
#pragma unroll
  for (int qf=0; qf<2; qf++){
    lrun[qf] += __shfl_xor(lrun[qf], 16, 64);
    lrun[qf] += __shfl_xor(lrun[qf], 32, 64);
    float inv = 1.0f/lrun[qf];
    int t = qbase + qf*16 + c;
#pragma unroll
    for (int df=0; df<4; df++){
      uint2 pr;
      pr.x = pk2(oacc[df][qf][1]*inv, oacc[df][qf][0]*inv);
      pr.y = pk2(oacc[df][qf][3]*inv, oacc[df][qf][2]*inv);
      *(uint2*)(O + ((size_t)b*TSEQ + t)*CDIM + h*HD + df*16 + 4*g) = pr;
    }
  }
}

extern "C" void kernel_launch(void* const* d_in, const int* in_sizes, int n_in,
                              void* d_out, int out_size, void* d_ws, size_t ws_size,
                              hipStream_t stream){
  (void)in_sizes; (void)n_in; (void)out_size; (void)ws_size;
  const float* x1 = (const float*)d_in[0];
  const float* x2 = (const float*)d_in[1];
  const float* Wq = (const float*)d_in[2];
  const float* bq = (const float*)d_in[3];
  const float* Wk = (const float*)d_in[4];
  const float* bk = (const float*)d_in[5];
  const float* Wv = (const float*)d_in[6];
  const float* bv = (const float*)d_in[7];
  const float* Wu = (const float*)d_in[8];
  const float* bu = (const float*)d_in[9];

  unsigned short* ws = (unsigned short*)d_ws;
  size_t o = 0;
  unsigned short* x1b = ws + o; o += (size_t)MR*CDIM;
  unsigned short* x2b = ws + o; o += (size_t)MR*CDIM;
  unsigned short* wqb = ws + o; o += (size_t)CDIM*CDIM;
  unsigned short* wkb = ws + o; o += (size_t)CDIM*CDIM;
  unsigned short* wvb = ws + o; o += (size_t)CDIM*CDIM;
  unsigned short* wub = ws + o; o += (size_t)CDIM*CDIM;
  unsigned short* Qb  = ws + o; o += (size_t)MR*CDIM;
  unsigned short* Kbf = ws + o; o += (size_t)MR*CDIM;
  unsigned short* Vtb = ws + o; o += (size_t)MR*CDIM;
  unsigned short* Ob  = x1b;   // x1b dead after QKV GEMM; reuse for attention output

  conv_x<<<dim3((MR*CDIM)/1024, 2),   256, 0, stream>>>(x1, x2, x1b, x2b);
  conv_w<<<dim3((CDIM*CDIM)/1024, 4), 256, 0, stream>>>(Wq, Wk, Wv, Wu, wqb, wkb, wvb, wub);

  gemm_qkv<<<dim3(MR/256, CDIM/128, 3), 512, 0, stream>>>(
      x1b, x2b, wqb, wkb, wvb, bq, bk, bv, Qb, Kbf, Vtb);
  attn_kernel<<<dim3(1024), 256, 0, stream>>>(Qb, Kbf, Vtb, Ob);
  gemm_u<<<dim3(MR/256, CDIM/128), 512, 0, stream>>>(Ob, wub, bu, (float*)d_out);
}

// Round 3
// 318.838 us; speedup vs baseline: 1.1062x; 1.0369x over previous
//
#include <hip/hip_runtime.h>

#define TSEQ 2048
#define BB 4
#define CDIM 1024
#define NH 16
#define HD 64
#define MR (TSEQ*BB)   // 8192 rows
#define C2SCALE 0.045084220f   // log2(e)/sqrt(CDIM) = log2(e)/32

typedef __attribute__((ext_vector_type(8))) short sh8;   // 8 bf16 = 4 VGPRs
typedef __attribute__((ext_vector_type(4))) short sh4;   // 4 bf16
typedef __attribute__((ext_vector_type(4))) float f4;    // MFMA C/D
typedef __attribute__((ext_vector_type(4))) unsigned int u32x4;

__device__ __forceinline__ unsigned short f2bf(float x){
  unsigned u = __builtin_bit_cast(unsigned, x);
  u += 0x7fffu + ((u>>16)&1u);          // round-to-nearest-even
  return (unsigned short)(u>>16);
}

// pack two floats -> two bf16 (round-half-up) in one dword: [hi16(a) : hi16(b)]
__device__ __forceinline__ unsigned pk2(float a, float b){
  unsigned ua = __builtin_bit_cast(unsigned, a) + 0x8000u;
  unsigned ub = __builtin_bit_cast(unsigned, b) + 0x8000u;
  return __builtin_amdgcn_perm(ua, ub, 0x07060302u);  // bytes a[3],a[2],b[3],b[2]
}

__device__ __forceinline__ void gll16(const unsigned short* g, unsigned short* l){
  __builtin_amdgcn_global_load_lds(
      (const __attribute__((address_space(1))) unsigned int*)g,
      (__attribute__((address_space(3))) unsigned int*)l, 16, 0, 0);
}

// ---------------- fp32 -> bf16 conversion, fused ----------------
__global__ void conv_x(const float* __restrict__ a, const float* __restrict__ b,
                       unsigned short* __restrict__ ya, unsigned short* __restrict__ yb){
  const float* s = blockIdx.y ? b : a;
  unsigned short* d = blockIdx.y ? yb : ya;
  int i = (blockIdx.x*256 + threadIdx.x)*4;
  f4 v = *(const f4*)(s+i);
  sh4 o;
  o.x = (short)f2bf(v.x); o.y = (short)f2bf(v.y);
  o.z = (short)f2bf(v.z); o.w = (short)f2bf(v.w);
  *(sh4*)(d+i) = o;
}

__global__ void conv_w(const float* __restrict__ w0, const float* __restrict__ w1,
                       const float* __restrict__ w2, const float* __restrict__ w3,
                       unsigned short* __restrict__ y0, unsigned short* __restrict__ y1,
                       unsigned short* __restrict__ y2, unsigned short* __restrict__ y3){
  const float* s; unsigned short* d;
  switch(blockIdx.y){
    case 0: s=w0; d=y0; break;
    case 1: s=w1; d=y1; break;
    case 2: s=w2; d=y2; break;
    default: s=w3; d=y3; break;
  }
  int i = (blockIdx.x*256 + threadIdx.x)*4;
  f4 v = *(const f4*)(s+i);
  sh4 o;
  o.x = (short)f2bf(v.x); o.y = (short)f2bf(v.y);
  o.z = (short)f2bf(v.z); o.w = (short)f2bf(v.w);
  *(sh4*)(d+i) = o;
}

// ================= deep-pipelined GEMM core =================
// BM=256, BN=128, BK=64, 512 threads = 8 waves (4M x 2N), per-wave 64x64.
// 3-deep LDS ring (3 x 48KB), stages 2 K-tiles ahead, counted vmcnt(6).
// Round-3 change: removed the sched_barrier(0) order-pinning after every
// s_barrier (m141 failure mode: pinning defeats the compiler scheduler,
// lands at ~510 TF -- exactly what round 2 measured). Ordering safety is
// preserved by the "memory" clobbers on the vmcnt asm (loads can't hoist
// above them, glls can't sink below) and by s_barrier's side-effect
// scheduling boundary. Race analysis unchanged from round 2.
#define NKT 16          // CDIM/64
#define BUFS 24576      // shorts per ring slot (A 16384 + B 8192)

__device__ __forceinline__ void gemm_core(
    const unsigned short* __restrict__ Aglob, const unsigned short* __restrict__ Bglob,
    unsigned short* smem, int m0, int n0, int tid, f4 (&acc)[4][4])
{
  const int wave = tid>>6, lane = tid&63;
  const int g = lane>>4, c = lane&15;
  const int wr = wave>>1, wc = wave&1;

  // staging precompute: A slots i*512+tid (i<4), B slots i*512+tid (i<2)
  const unsigned short* aSrc[4]; int aOff[4];
  const unsigned short* bSrc[2]; int bOff[2];
#pragma unroll
  for (int i=0;i<4;i++){
    int slot = i*512+tid; int row = slot>>3, ch = slot&7;
    aSrc[i] = Aglob + (size_t)(m0+row)*CDIM + (ch^(row&7))*8;
    aOff[i] = slot*8;
  }
#pragma unroll
  for (int i=0;i<2;i++){
    int slot = i*512+tid; int row = slot>>3, ch = slot&7;
    bSrc[i] = Bglob + (size_t)(n0+row)*CDIM + (ch^(row&7))*8;
    bOff[i] = 16384 + slot*8;
  }
  const int arow = wr*64 + c;        // + mt*16
  const int brow = wc*64 + c;        // + nt*16
  const int ch0 = g ^ (c&7);         // ks=0 swizzled chunk
  const int ch1 = (4+g) ^ (c&7);     // ks=1

  // prologue: stage tiles 0 and 1
#pragma unroll
  for (int i=0;i<4;i++) gll16(aSrc[i],     smem + aOff[i]);
#pragma unroll
  for (int i=0;i<2;i++) gll16(bSrc[i],     smem + bOff[i]);
#pragma unroll
  for (int i=0;i<4;i++) gll16(aSrc[i]+64,  smem + BUFS + aOff[i]);
#pragma unroll
  for (int i=0;i<2;i++) gll16(bSrc[i]+64,  smem + BUFS + bOff[i]);
  asm volatile("s_waitcnt vmcnt(6)" ::: "memory");   // tile 0 landed
  __builtin_amdgcn_s_barrier();

  int q = 0;
  for (int kt=0; kt<NKT; kt++){
    unsigned short* bufc = smem + q*BUFS;
    int r = q+2; if (r>=3) r-=3;                 // stage target ring slot
    unsigned short* dst = smem + r*BUFS;
    const int koff = (kt+2)*64;
    // ---------- ph1: A frags + B n0-1, stage A of tile kt+2 ----------
    sh8 af[4][2], bfr[2][2];
#pragma unroll
    for (int mt=0;mt<4;mt++){
      af[mt][0] = *(const sh8*)(bufc + (arow+mt*16)*64 + ch0*8);
      af[mt][1] = *(const sh8*)(bufc + (arow+mt*16)*64 + ch1*8);
    }
#pragma unroll
    for (int nt=0;nt<2;nt++){
      bfr[nt][0] = *(const sh8*)(bufc + 16384 + (brow+nt*16)*64 + ch0*8);
      bfr[nt][1] = *(const sh8*)(bufc + 16384 + (brow+nt*16)*64 + ch1*8);
    }
    if (kt+2 < NKT){
#pragma unroll
      for (int i=0;i<4;i++) gll16(aSrc[i]+koff, dst + aOff[i]);
    }
    __builtin_amdgcn_s_barrier();
    __builtin_amdgcn_s_setprio(1);
#pragma unroll
    for (int mt=0;mt<4;mt++)
#pragma unroll
      for (int nt=0;nt<2;nt++){
        acc[mt][nt] = __builtin_amdgcn_mfma_f32_16x16x32_bf16(af[mt][0], bfr[nt][0], acc[mt][nt],0,0,0);
        acc[mt][nt] = __builtin_amdgcn_mfma_f32_16x16x32_bf16(af[mt][1], bfr[nt][1], acc[mt][nt],0,0,0);
      }
    __builtin_amdgcn_s_setprio(0);
    __builtin_amdgcn_s_barrier();
    // ---------- ph2: B n2-3, stage B of tile kt+2, counted vmcnt ----------
#pragma unroll
    for (int nt=0;nt<2;nt++){
      bfr[nt][0] = *(const sh8*)(bufc + 16384 + (brow+(nt+2)*16)*64 + ch0*8);
      bfr[nt][1] = *(const sh8*)(bufc + 16384 + (brow+(nt+2)*16)*64 + ch1*8);
    }
    if (kt+2 < NKT){
#pragma unroll
      for (int i=0;i<2;i++) gll16(bSrc[i]+koff, dst + bOff[i]);
    }
    __builtin_amdgcn_s_barrier();
    __builtin_amdgcn_s_setprio(1);
#pragma unroll
    for (int mt=0;mt<4;mt++)
#pragma unroll
      for (int nt=0;nt<2;nt++){
        acc[mt][nt+2] = __builtin_amdgcn_mfma_f32_16x16x32_bf16(af[mt][0], bfr[nt][0], acc[mt][nt+2],0,0,0);
        acc[mt][nt+2] = __builtin_amdgcn_mfma_f32_16x16x32_bf16(af[mt][1], bfr[nt][1], acc[mt][nt+2],0,0,0);
      }
    __builtin_amdgcn_s_setprio(0);
    if (kt < NKT-1){
      if (kt < NKT-2) asm volatile("s_waitcnt vmcnt(6)" ::: "memory");  // tile kt+1 landed
      else            asm volatile("s_waitcnt vmcnt(0)" ::: "memory");  // tail drain
    }
    __builtin_amdgcn_s_barrier();
    q = (q==2)?0:q+1;
  }
}

// ---------------- final GEMM: C[m][n] = sum_k A[m][k]*W[n][k] + bias[n], fp32 out ----
__global__ __launch_bounds__(512,2) void gemm_u(
    const unsigned short* __restrict__ A, const unsigned short* __restrict__ Bw,
    const float* __restrict__ bias, float* __restrict__ Cout){
  __shared__ unsigned short smem[3*BUFS];
  const int tid  = threadIdx.x;
  const int wave = tid>>6, lane = tid&63;
  const int g = lane>>4, c = lane&15;
  const int m0 = blockIdx.x*256, n0 = blockIdx.y*128;
  const int wr = wave>>1, wc = wave&1;
  f4 acc[4][4] = {};
  gemm_core(A, Bw, smem, m0, n0, tid, acc);

#pragma unroll
  for (int nt=0; nt<4; nt++){
    int nn = n0 + wc*64 + nt*16 + c;
    float bsv = bias[nn];
#pragma unroll
    for (int mt=0; mt<4; mt++){
      int mb = m0 + wr*64 + mt*16 + 4*g;
#pragma unroll
      for (int r=0; r<4; r++)
        Cout[(size_t)(mb+r)*CDIM + nn] = acc[mt][nt][r] + bsv;
    }
  }
}

// ---------------- fused Q/K/V projection: blockIdx.z selects output ----------------
// z=0: Q = x1@Wq^T+bq, scaled by C2SCALE, bf16 row-major
// z=1: K = x2@Wk^T+bk, bf16 row-major
// z=2: V = x2@Wv^T+bv, bf16 transposed to (b,h,d,t)
__global__ __launch_bounds__(512,2) void gemm_qkv(
    const unsigned short* __restrict__ x1b, const unsigned short* __restrict__ x2b,
    const unsigned short* __restrict__ wq, const unsigned short* __restrict__ wk,
    const unsigned short* __restrict__ wv,
    const float* __restrict__ bq, const float* __restrict__ bk, const float* __restrict__ bv,
    unsigned short* __restrict__ Qo, unsigned short* __restrict__ Ko,
    unsigned short* __restrict__ Vo){
  __shared__ unsigned short smem[3*BUFS];
  const int z = blockIdx.z;
  const unsigned short* A  = (z==0) ? x1b : x2b;
  const unsigned short* Bw = (z==0) ? wq : (z==1) ? wk : wv;
  const float* bias        = (z==0) ? bq : (z==1) ? bk : bv;
  const int tid  = threadIdx.x;
  const int wave = tid>>6, lane = tid&63;
  const int g = lane>>4, c = lane&15;
  const int m0 = blockIdx.x*256, n0 = blockIdx.y*128;
  const int wr = wave>>1, wc = wave&1;
  f4 acc[4][4] = {};
  gemm_core(A, Bw, smem, m0, n0, tid, acc);

#pragma unroll
  for (int nt=0; nt<4; nt++){
    int nn = n0 + wc*64 + nt*16 + c;
    float bsv = bias[nn];
#pragma unroll
    for (int mt=0; mt<4; mt++){
      int mb = m0 + wr*64 + mt*16 + 4*g;
#pragma unroll
      for (int r=0; r<4; r++){
        float v = acc[mt][nt][r] + bsv;
        int mm = mb + r;
        if (z==0){
          Qo[(size_t)mm*CDIM + nn] = f2bf(v*C2SCALE);
        } else if (z==1){
          Ko[(size_t)mm*CDIM + nn] = f2bf(v);
        } else {
          int t = mm>>2, bb = mm&3, h = nn>>6, d = nn&63;
          Vo[(((size_t)bb*NH + h)*HD + d)*TSEQ + t] = f2bf(v);
        }
      }
    }
  }
}

// ---------------- flash attention, S^T / O^T -----------------------------------
// Round-3 change: round 2 measured 25% occupancy = 3 blocks/CU resident vs 4
// blocks/CU of work -> half the kernel ran 1-resident (tail). Fix: 4 blocks/CU
// with exact 4/CU packing. Reg-staging (32 VGPR) replaced by DIRECT
// global_load_lds: global source is already pre-swizzled + LDS dest linear
// (rule #21 pattern). KVBLK=64 double-buffered tiles (2 x 16KB = same 32KB
// LDS): gll16 into idle buffer issued at iter-top, loads fly during the whole
// compute phase; __syncthreads' vmcnt(0) drain at iter-end is then free
// (T3 minimum 2-phase recipe). sacc shrunk to [2][2] (compute/consume S per
// 32-key group). ~110 VGPR total -> __launch_bounds__(256,4).
__global__ __launch_bounds__(256,4) void attn_kernel(
    const unsigned short* __restrict__ Q, const unsigned short* __restrict__ Kb,
    const unsigned short* __restrict__ Vt, unsigned short* __restrict__ O){
  __shared__ unsigned short Ks[2][64*64];      // (key, d), chunk ^= row&7
  __shared__ unsigned short Vs[2][64*64];      // (d, key), chunk ^= d&7
  const int tid=threadIdx.x, wave=tid>>6, lane=tid&63;
  const int g=lane>>4, c=lane&15;
  const bool godd = (g&1);
  const int gx = blockIdx.x;                   // 1024 linear blocks
  const int bh = ((gx>>7)<<3) | (gx&7);        // all 16 qts of a bh share gx%8 (same XCD)
  const int qt = (gx>>3)&15;
  const int b = bh>>4, h = bh&15;
  const int qbase = qt*128 + wave*32;

  // staging bases: per thread 2 gll16 for K, 2 for V, per 64-key tile
  const unsigned short* kb0[2];
  const unsigned short* vb0[2];
#pragma unroll
  for (int i=0; i<2; i++){
    int cc = i*256+tid;
    int krow = cc>>3, kch = (cc&7) ^ (krow&7);
    kb0[i] = Kb + ((size_t)krow*BB + b)*CDIM + h*HD + kch*8;
    int vd = cc>>3, vch = (cc&7) ^ (vd&7);
    vb0[i] = Vt + ((size_t)(b*NH+h)*HD + vd)*TSEQ + vch*8;
  }

  sh8 qfr[2][2];
#pragma unroll
  for (int qf=0; qf<2; qf++)
#pragma unroll
    for (int kc=0; kc<2; kc++){
      int t = qbase + qf*16 + c;
      qfr[qf][kc] = *(const sh8*)(Q + ((size_t)t*BB + b)*CDIM + h*HD + kc*32 + g*8);
    }

  f4 oacc[4][2] = {};                          // O^T frags: [d-frag][q-frag]
  float lrun[2] = {0.f, 0.f};                  // lane-local partial denominators

  // prologue: stage tile 0 into buffer 0
#pragma unroll
  for (int i=0; i<2; i++){
    gll16(kb0[i], Ks[0] + (i*256+tid)*8);
    gll16(vb0[i], Vs[0] + (i*256+tid)*8);
  }
  __syncthreads();                             // drains vmcnt(0): tile 0 resident

  const int NT = TSEQ/64;                      // 32 tiles
  int cur = 0;
  for (int it=0; it<NT; it++){
    // issue next tile's global->LDS loads into the idle buffer (in flight
    // during the compute below; __syncthreads at iter end drains them)
    if (it+1 < NT){
      int k0n = (it+1)*64;
#pragma unroll
      for (int i=0; i<2; i++){
        gll16(kb0[i] + (size_t)k0n*BB*CDIM, Ks[cur^1] + (i*256+tid)*8);
        gll16(vb0[i] + k0n,                 Vs[cur^1] + (i*256+tid)*8);
      }
    }
    const unsigned short* ks = Ks[cur];
    const unsigned short* vs = Vs[cur];

    // per 32-key group: S^T MFMA -> exp2 + in-register transpose -> PV MFMA
#pragma unroll
    for (int sub=0; sub<2; sub++){
      f4 sacc[2][2] = {};
      __builtin_amdgcn_s_setprio(1);
#pragma unroll
      for (int j=0; j<2; j++){
        int kf = sub*2 + j;
        sh8 af[2];
#pragma unroll
        for (int kc=0; kc<2; kc++){
          int ch = (kc*4+g) ^ (c&7);
          af[kc] = *(const sh8*)(ks + (kf*16+c)*64 + ch*8);
        }
#pragma unroll
        for (int kc=0; kc<2; kc++)
#pragma unroll
          for (int qf=0; qf<2; qf++)
            sacc[j][qf] = __builtin_amdgcn_mfma_f32_16x16x32_bf16(af[kc], qfr[qf][kc], sacc[j][qf],0,0,0);
      }
      __builtin_amdgcn_s_setprio(0);

      sh8 pf[2];
#pragma unroll
      for (int qf=0; qf<2; qf++){
        f4 sa = sacc[0][qf];
        f4 sb = sacc[1][qf];
        float pa0 = __builtin_amdgcn_exp2f(sa[0]);
        float pa1 = __builtin_amdgcn_exp2f(sa[1]);
        float pa2 = __builtin_amdgcn_exp2f(sa[2]);
        float pa3 = __builtin_amdgcn_exp2f(sa[3]);
        float pb0 = __builtin_amdgcn_exp2f(sb[0]);
        float pb1 = __builtin_amdgcn_exp2f(sb[1]);
        float pb2 = __builtin_amdgcn_exp2f(sb[2]);
        float pb3 = __builtin_amdgcn_exp2f(sb[3]);
        lrun[qf] += ((pa0+pa1)+(pa2+pa3)) + ((pb0+pb1)+(pb2+pb3));
        // dwords: low short = even key, high short = odd key
        unsigned A0 = pk2(pa1, pa0);   // keys 4g+{0,1} of kf=sub*2
        unsigned A1 = pk2(pa3, pa2);   // keys 4g+{2,3}
        unsigned B0 = pk2(pb1, pb0);   // keys 4g+{0,1} of kf=sub*2+1
        unsigned B1 = pk2(pb3, pb2);
        // exchange: A' = {A.lo32lanes ; B.lo32lanes}, B' = {A.hi ; B.hi}
        asm("v_permlane32_swap_b32 %0, %1" : "+v"(A0), "+v"(B0));
        asm("v_permlane32_swap_b32 %0, %1" : "+v"(A1), "+v"(B1));
        // g <-> g^1 movement (xor 16 within each 32-lane half)
        unsigned xA0 = (unsigned)__builtin_amdgcn_ds_swizzle((int)A0, 0x401F);
        unsigned xA1 = (unsigned)__builtin_amdgcn_ds_swizzle((int)A1, 0x401F);
        unsigned xB0 = (unsigned)__builtin_amdgcn_ds_swizzle((int)B0, 0x401F);
        unsigned xB1 = (unsigned)__builtin_amdgcn_ds_swizzle((int)B1, 0x401F);
        u32x4 pw;
        pw.x = godd ? xB0 : A0;   // keys g*8+{0,1}
        pw.y = godd ? xB1 : A1;   // keys g*8+{2,3}
        pw.z = godd ? B0  : xA0;  // keys g*8+{4,5}
        pw.w = godd ? B1  : xA1;  // keys g*8+{6,7}
        pf[qf] = __builtin_bit_cast(sh8, pw);
      }
      __builtin_amdgcn_s_setprio(1);
#pragma unroll
      for (int df=0; df<4; df++){
        int ch = (sub*4+g) ^ (c&7);
        sh8 vf = *(const sh8*)(vs + (df*16+c)*64 + ch*8);
#pragma unroll
        for (int qf=0; qf<2; qf++)
          oacc[df][qf] = __builtin_amdgcn_mfma_f32_16x16x32_bf16(vf, pf[qf], oacc[df][qf],0,0,0);
      }
      __builtin_amdgcn_s_setprio(0);
    }

    __syncthreads();     // drains this wave's glls (vmcnt 0) + all waves done reading
    cur ^= 1;
  }

  // cross-lane denominator reduction (over g groups), then normalize + store
#pragma unroll
  for (int qf=0; qf<2; qf++){
    lrun[qf] += __shfl_xor(lrun[qf], 16, 64);
    lrun[qf] += __shfl_xor(lrun[qf], 32, 64);
    float inv = 1.0f/lrun[qf];
    int t = qbase + qf*16 + c;
#pragma unroll
    for (int df=0; df<4; df++){
      uint2 pr;
      pr.x = pk2(oacc[df][qf][1]*inv, oacc[df][qf][0]*inv);
      pr.y = pk2(oacc[df][qf][3]*inv, oacc[df][qf][2]*inv);
      *(uint2*)(O + ((size_t)b*TSEQ + t)*CDIM + h*HD + df*16 + 4*g) = pr;
    }
  }
}

extern "C" void kernel_launch(void* const* d_in, const int* in_sizes, int n_in,
                              void* d_out, int out_size, void* d_ws, size_t ws_size,
                              hipStream_t stream){
  (void)in_sizes; (void)n_in; (void)out_size; (void)ws_size;
  const float* x1 = (const float*)d_in[0];
  const float* x2 = (const float*)d_in[1];
  const float* Wq = (const float*)d_in[2];
  const float* bq = (const float*)d_in[3];
  const float* Wk = (const float*)d_in[4];
  const float* bk = (const float*)d_in[5];
  const float* Wv = (const float*)d_in[6];
  const float* bv = (const float*)d_in[7];
  const float* Wu = (const float*)d_in[8];
  const float* bu = (const float*)d_in[9];

  unsigned short* ws = (unsigned short*)d_ws;
  size_t o = 0;
  unsigned short* x1b = ws + o; o += (size_t)MR*CDIM;
  unsigned short* x2b = ws + o; o += (size_t)MR*CDIM;
  unsigned short* wqb = ws + o; o += (size_t)CDIM*CDIM;
  unsigned short* wkb = ws + o; o += (size_t)CDIM*CDIM;
  unsigned short* wvb = ws + o; o += (size_t)CDIM*CDIM;
  unsigned short* wub = ws + o; o += (size_t)CDIM*CDIM;
  unsigned short* Qb  = ws + o; o += (size_t)MR*CDIM;
  unsigned short* Kbf = ws + o; o += (size_t)MR*CDIM;
  unsigned short* Vtb = ws + o; o += (size_t)MR*CDIM;
  unsigned short* Ob  = x1b;   // x1b dead after QKV GEMM; reuse for attention output

  conv_x<<<dim3((MR*CDIM)/1024, 2),   256, 0, stream>>>(x1, x2, x1b, x2b);
  conv_w<<<dim3((CDIM*CDIM)/1024, 4), 256, 0, stream>>>(Wq, Wk, Wv, Wu, wqb, wkb, wvb, wub);

  gemm_qkv<<<dim3(MR/256, CDIM/128, 3), 512, 0, stream>>>(
      x1b, x2b, wqb, wkb, wvb, bq, bk, bv, Qb, Kbf, Vtb);
  attn_kernel<<<dim3(1024), 256, 0, stream>>>(Qb, Kbf, Vtb, Ob);
  gemm_u<<<dim3(MR/256, CDIM/128), 512, 0, stream>>>(Ob, wub, bu, (float*)d_out);
}